// Round 7
// baseline (227.906 us; speedup 1.0000x reference)
//
#include <hip/hip_runtime.h>
#include <hip/hip_bf16.h>
#include <stdint.h>

#define B_ 2
#define S_ 2048
#define D_ 1024
#define H_ 16
#define DK_ 64

typedef __attribute__((ext_vector_type(4))) float floatx4;
typedef __attribute__((ext_vector_type(8))) short shortx8;
typedef __attribute__((ext_vector_type(4))) short shortx4;
typedef unsigned short ushort_t;

// f32 -> bf16 round-to-nearest-even (used for GEMM outputs)
__device__ inline ushort_t f2bf(float f) {
  union { float f; unsigned u; } v; v.f = f;
  unsigned r = v.u + 0x7FFFu + ((v.u >> 16) & 1u);
  return (ushort_t)(r >> 16);
}

// pack two f32 -> bf16x2 by truncation (1 v_perm); fine for P >= 0 / O
__device__ inline unsigned pack2bf(float lo, float hi) {
  return __builtin_amdgcn_perm(__float_as_uint(hi), __float_as_uint(lo), 0x07060302u);
}

__device__ inline shortx4 mk_sx4(unsigned lo, unsigned hi) {
  union { unsigned u[2]; shortx4 s; } v; v.u[0] = lo; v.u[1] = hi; return v.s;
}

__device__ inline float fast_exp2(float x) {
#if __has_builtin(__builtin_amdgcn_exp2f)
  return __builtin_amdgcn_exp2f(x);
#else
  return __expf(0.69314718056f * x);
#endif
}

__device__ inline void gload_lds16(const void* g, void* l) {
  __builtin_amdgcn_global_load_lds(
      (const __attribute__((address_space(1))) unsigned int*)g,
      (__attribute__((address_space(3))) unsigned int*)l, 16, 0, 0);
}

__device__ inline floatx4 mfma16x16x16bf16(shortx4 a, shortx4 b, floatx4 c) {
#if __has_builtin(__builtin_amdgcn_mfma_f32_16x16x16bf16_1k)
  return __builtin_amdgcn_mfma_f32_16x16x16bf16_1k(a, b, c, 0, 0, 0);
#else
  floatx4 d;
  asm("v_mfma_f32_16x16x16_bf16 %0, %1, %2, %3" : "=v"(d) : "v"(a), "v"(b), "v"(c));
  return d;
#endif
}

// ---------------- fp32 -> bf16 conversion (7 tensors fused) ----------------
// Round-8 failure: fusing into the GEMM via global->VGPR->ds_write serialized
// (no async queue). Round-13 failure: staging f32 A directly doubled staging
// bytes + cvt VALU and conflicted anyway (43->82 us). Conversion stays
// standalone (pure-BW, ~23 us).
struct ConvArgs {
  const float* src[7];
  ushort_t* dst[7];
};

__global__ __launch_bounds__(256) void convert_kernel(ConvArgs a) {
  int blk = blockIdx.x;
  int seg, bis;
  if (blk < 3072) { seg = blk >> 10; bis = blk & 1023; }
  else { int bb = blk - 3072; seg = 3 + (bb >> 8); bis = bb & 255; }
  const float4* src = (const float4*)(a.src[seg]) + (size_t)bis * 1024;
  ushort4* dst = (ushort4*)(a.dst[seg]) + (size_t)bis * 1024;
#pragma unroll
  for (int i = 0; i < 4; ++i) {
    int idx = i * 256 + threadIdx.x;
    float4 v = src[idx];
    ushort4 o;
    o.x = f2bf(v.x); o.y = f2bf(v.y); o.z = f2bf(v.z); o.w = f2bf(v.w);
    dst[idx] = o;
  }
}

// ---------------- GEMM: C[m][n] = (sum_k A[m][k]*W[n][k] + bias[n])*scl ----
// 2-phase schedule + BK=64, 128B rows, 8-chunk XOR swizzle (stored chunk =
// logical ^ (row&7); pre-swizzled global source, linear gload_lds dest,
// XOR'd ds_read). Conflict-free (R1/R5/R6 counter-proven: SQ_LDS_BANK_
// CONFLICT == 0). Halves the barrier count vs BK=32.
// Round 16: qkv moves from TM=128 (64KB LDS, 2 blocks/CU, Occ 14%, MfmaUtil
// 22%, latency-exposed) to TM=64 (48KB, 3 blocks/CU, 1536-block grid) --
// the more-blocks/CU lever that paid off in R0->R2 (GEMM) and R5->R6
// (attn). Cost: W re-staged per 64-row m-tile (2x L2 traffic, 20x headroom)
// and 16:12 MFMA:ds_read per wave-iter vs 32:16.
// outmode: 0 = bf16 row-major, 1 = f32 row-major,
//          2 = bf16 V-transpose out[(b*1024+n)*2048 + s], m = b*2048+s.
template <int TM>
__device__ inline void gemm_bk64_core(const ushort_t* __restrict__ A,
                                      const ushort_t* __restrict__ W,
                                      const float* __restrict__ bias,
                                      float scl,
                                      void* __restrict__ outp,
                                      int m0, int n0, int N, int K, int outmode) {
  constexpr int GA = TM / 8;        // A gloads (8 rows of 128B each)
  constexpr int GB = 16;            // B gloads (128 rows)
  constexpr int GW = (GA + GB) / 4; // gloads per wave
  constexpr int MI = TM / 32;       // m-frags per wave
  constexpr int BUFB = (TM + 128) * 128;  // bytes per buffer
  __shared__ uint4 smem4[2 * BUFB / 16];
  char* smem = (char*)&smem4[0];

  const int tid = threadIdx.x;
  const int wave = tid >> 6;
  const int lane = tid & 63;
  const int quad = lane >> 4;
  const int l16 = lane & 15;
  const int wm = (wave >> 1) * (TM / 2);
  const int wn = (wave & 1) * 64;

  floatx4 acc[MI][4] = {};

  // staging: gload g covers 8 rows x 128B; lane -> row g*8+(lane>>3),
  // stored chunk (lane&7) holds global chunk (lane&7)^(lane>>3).
  const ushort_t* gsrc[GW];
  int ldst[GW];
#pragma unroll
  for (int i = 0; i < GW; ++i) {
    int g = wave * GW + i;
    int r8 = lane >> 3;
    int cs = ((lane & 7) ^ r8) * 8;  // ushort offset of swizzled source chunk
    if (g < GA) {
      gsrc[i] = A + (size_t)(m0 + g * 8 + r8) * K + cs;
      ldst[i] = g * 1024 + lane * 16;
    } else {
      gsrc[i] = W + (size_t)(n0 + (g - GA) * 8 + r8) * K + cs;
      ldst[i] = TM * 128 + (g - GA) * 1024 + lane * 16;
    }
  }

#pragma unroll
  for (int i = 0; i < GW; ++i) gload_lds16(gsrc[i], smem + ldst[i]);

  const int niter = K >> 6;
  for (int j = 0; j < niter; ++j) {
    __syncthreads();
    if (j + 1 < niter) {
      const int ko = (j + 1) * 64;
      char* bufn = smem + ((j + 1) & 1) * BUFB;
#pragma unroll
      for (int i = 0; i < GW; ++i) gload_lds16(gsrc[i] + ko, bufn + ldst[i]);
    }
    const char* aT = smem + (j & 1) * BUFB;
    const char* bT = aT + TM * 128;
    // frag reads: row r at byte r*128; k-step ks chunk (ks*4+quad)^(r&7).
    shortx8 af[MI][2], bf[4][2];
#pragma unroll
    for (int ks = 0; ks < 2; ++ks) {
      const int co = ((ks * 4 + quad) ^ (l16 & 7)) * 16;
#pragma unroll
      for (int mi = 0; mi < MI; ++mi)
        af[mi][ks] = *(const shortx8*)(aT + (wm + mi * 16 + l16) * 128 + co);
#pragma unroll
      for (int ni = 0; ni < 4; ++ni)
        bf[ni][ks] = *(const shortx8*)(bT + (wn + ni * 16 + l16) * 128 + co);
    }
#pragma unroll
    for (int ks = 0; ks < 2; ++ks)
#pragma unroll
      for (int mi = 0; mi < MI; ++mi)
#pragma unroll
        for (int ni = 0; ni < 4; ++ni)
          acc[mi][ni] = __builtin_amdgcn_mfma_f32_16x16x32_bf16(af[mi][ks], bf[ni][ks], acc[mi][ni], 0, 0, 0);
  }

  // epilogue: C/D layout col=lane&15, row=quad*4+r
#pragma unroll
  for (int ni = 0; ni < 4; ++ni) {
    int n = n0 + wn + ni * 16 + l16;
    float bv = bias[n];
#pragma unroll
    for (int mi = 0; mi < MI; ++mi) {
      if (outmode == 2) {
        int m = m0 + wm + mi * 16 + quad * 4;
        int b = m >> 11, s = m & 2047;
        ushort_t* dst = (ushort_t*)outp + (((size_t)(b * 1024 + n)) << 11) + s;
        uint2 pk;
        pk.x = (unsigned)f2bf(acc[mi][ni][0] + bv) |
               ((unsigned)f2bf(acc[mi][ni][1] + bv) << 16);
        pk.y = (unsigned)f2bf(acc[mi][ni][2] + bv) |
               ((unsigned)f2bf(acc[mi][ni][3] + bv) << 16);
        *(uint2*)(dst) = pk;  // single 8B store (8B-aligned: s = quad*4)
      } else {
#pragma unroll
        for (int r = 0; r < 4; ++r) {
          int m = m0 + wm + mi * 16 + quad * 4 + r;
          float v = (acc[mi][ni][r] + bv) * scl;
          if (outmode == 1) ((float*)outp)[(size_t)m * N + n] = v;
          else ((ushort_t*)outp)[(size_t)m * N + n] = f2bf(v);
        }
      }
    }
  }
}

struct QkvArgs {
  const ushort_t* A[3];
  const ushort_t* W[3];
  const float* bias[3];
  ushort_t* out[3];
  float scale[3];
};

// Round 16: grid (8,64,3), TM=64 tiles (48KB LDS -> 3 blocks/CU, 12 waves).
// XCD swizzle: flat%8 == blockIdx.x -> XCD c's working set = 512 A-rows
// (1MB) + full W (2MB) < 4MB L2.
// z==2 (V) writes the transposed layout consumed by attention (fused vtrans).
__global__ __launch_bounds__(256) void gemm_qkv_kernel(QkvArgs a) {
  int z = blockIdx.z;
  int m0 = (blockIdx.x * 8 + (blockIdx.y >> 3)) * 64;
  int n0 = (blockIdx.y & 7) * 128;
  gemm_bk64_core<64>(a.A[z], a.W[z], a.bias[z], a.scale[z], a.out[z],
                     m0, n0, D_, D_, z == 2 ? 2 : 0);
}

// grid (8,64); 64x128 tiles, same swizzle principle.
__global__ __launch_bounds__(256) void gemm_out_kernel(const ushort_t* __restrict__ A,
                                                       const ushort_t* __restrict__ W,
                                                       const float* __restrict__ bias,
                                                       float* __restrict__ out) {
  int m0 = (blockIdx.x * 8 + (blockIdx.y >> 3)) * 64;
  int n0 = (blockIdx.y & 7) * 128;
  gemm_bk64_core<64>(A, W, bias, 1.0f, out, m0, n0, D_, D_, 1);
}

// ---------------- flash attention (causal), round 15 (validated R6) --------
// QBLK=64 (1 q-group/wave), K-tile 64, LDS 32KB -> 1024 blocks = 4/CU
// (launch_bounds(256,4)). Depth map: id = b*512 + u*16 + h; b=0: qt=31-u,
// b=1: qt=u -> CU c's 4 ids have depths summing to a CONSTANT 66.
// 8-chunk XOR swizzle on both K and V (R1/R5/R6-proven conflict-free).
// PV V-read chunk parity (kkb*2+(quad>>1)) separates quad pairs. setprio
// (T5) kept around both MFMA clusters.
__global__ __launch_bounds__(256, 4) void attn_kernel(const ushort_t* __restrict__ Qp,
                                                      const ushort_t* __restrict__ Kp,
                                                      const ushort_t* __restrict__ Vt,
                                                      ushort_t* __restrict__ O) {
  const int id = blockIdx.x;
  const int h = id & 15;
  const int u = (id >> 4) & 31;
  const int b = id >> 9;
  const int qt = b ? u : 31 - u;
  const int q0 = qt * 64;
  const int tid = threadIdx.x;
  const int wave = tid >> 6;
  const int lane = tid & 63;
  const int quad = lane >> 4;
  const int l16 = lane & 15;

  __shared__ ushort_t smem[2][8192];  // per buf: K[64][64] | V^T[64][64] = 16KB

  const size_t hoff = (size_t)h * DK_;

  // Q B-frags: lane holds Q[q=l16][d=ks*32+quad*8+i] (already exp2-scaled)
  shortx8 qf[2];
  {
    const ushort_t* qrow = Qp + ((size_t)b * S_ + q0 + wave * 16 + l16) * D_ + hoff;
    qf[0] = *(const shortx8*)(qrow + quad * 8);
    qf[1] = *(const shortx8*)(qrow + 32 + quad * 8);
  }

  // staging: per wave 2 K-gloads + 2 V-gloads, 8 rows x 8 chunks each;
  // stored chunk (lane&7) holds global chunk (lane&7)^(lane>>3).
  const int r8 = lane >> 3;
  const int cs8 = ((lane & 7) ^ r8) * 8;  // swizzled source chunk (ushorts)
  const ushort_t* kb[2];
  const ushort_t* vb[2];
  int kdst[2], vdst[2];
#pragma unroll
  for (int g = 0; g < 2; ++g) {
    const int tr = wave * 16 + g * 8 + r8;  // tile row 0..63
    kb[g] = Kp + ((size_t)b * S_ + tr) * D_ + hoff + cs8;
    vb[g] = Vt + ((size_t)(b * H_ + h) * 64 + tr) * (size_t)S_ + cs8;
    kdst[g] = (wave * 16 + g * 8) * 64 + lane * 8;         // ushort index
    vdst[g] = 4096 + (wave * 16 + g * 8) * 64 + lane * 8;
  }

  floatx4 oacc[4] = {};
  float l_run = 0.f;
  const int nj = qt + 1;

  // preload tile 0 into buffer 0
#pragma unroll
  for (int g = 0; g < 2; ++g) {
    gload_lds16(kb[g], &smem[0][kdst[g]]);
    gload_lds16(vb[g], &smem[0][vdst[g]]);
  }

  for (int j = 0; j < nj; ++j) {
    __syncthreads();
    if (j + 1 < nj) {
      ushort_t* bufn = smem[(j + 1) & 1];
      const size_t ko = (size_t)(j + 1) * 64 * D_;  // 64 k-rows ahead
      const int vo = (j + 1) * 64;                  // 64 k-cols ahead
#pragma unroll
      for (int g = 0; g < 2; ++g) {
        gload_lds16(kb[g] + ko, bufn + kdst[g]);
        gload_lds16(vb[g] + vo, bufn + vdst[g]);
      }
    }
    const ushort_t* k_lds = smem[j & 1];
    const ushort_t* v_lds = smem[j & 1] + 4096;

    // QK^T: S^T[kk=kkb*16+quad*4+r][q=l16]
    floatx4 sacc[4];
    __builtin_amdgcn_s_setprio(1);
#pragma unroll
    for (int kkb = 0; kkb < 4; ++kkb) {
      const ushort_t* krow = k_lds + (kkb * 16 + l16) * 64;
      shortx8 af0 = *(const shortx8*)(krow + (quad ^ (l16 & 7)) * 8);
      shortx8 af1 = *(const shortx8*)(krow + ((4 | quad) ^ (l16 & 7)) * 8);
      floatx4 acc = {0.f, 0.f, 0.f, 0.f};
      acc = __builtin_amdgcn_mfma_f32_16x16x32_bf16(af0, qf[0], acc, 0, 0, 0);
      acc = __builtin_amdgcn_mfma_f32_16x16x32_bf16(af1, qf[1], acc, 0, 0, 0);
      sacc[kkb] = acc;
    }
    __builtin_amdgcn_s_setprio(0);

    // diagonal masking (only the last tile can cross the diagonal)
    const int kbase = j * 64;
    if (kbase + 63 > q0 + wave * 16) {
      const int qg = q0 + wave * 16 + l16;
#pragma unroll
      for (int kkb = 0; kkb < 4; ++kkb)
#pragma unroll
        for (int r = 0; r < 4; ++r)
          if (kbase + kkb * 16 + quad * 4 + r > qg) sacc[kkb][r] = -3.0e38f;
    }

    // no-max softmax: p = exp2(s); per-lane partial l
    shortx4 pf[4];
    {
      float psum = 0.f;
#pragma unroll
      for (int kkb = 0; kkb < 4; ++kkb) {
        float p0 = fast_exp2(sacc[kkb][0]);
        float p1 = fast_exp2(sacc[kkb][1]);
        float p2 = fast_exp2(sacc[kkb][2]);
        float p3 = fast_exp2(sacc[kkb][3]);
        psum += (p0 + p1) + (p2 + p3);
        pf[kkb] = mk_sx4(pack2bf(p0, p1), pack2bf(p2, p3));
      }
      l_run += psum;
    }

    // PV: oacc[db] += V^T[d=db*16+l16][kk] * P^T; V chunk (kkb*2+(quad>>1))
    // ^ (l16&7), (quad&1) selects the 8B half -> 2-way max (free).
    __builtin_amdgcn_s_setprio(1);
#pragma unroll
    for (int kkb = 0; kkb < 4; ++kkb) {
      const int jj = ((kkb * 2 + (quad >> 1)) ^ (l16 & 7)) * 8 + (quad & 1) * 4;
#pragma unroll
      for (int db = 0; db < 4; ++db) {
        shortx4 vf = *(const shortx4*)(v_lds + (db * 16 + l16) * 64 + jj);
        oacc[db] = mfma16x16x16bf16(vf, pf[kkb], oacc[db]);
      }
    }
    __builtin_amdgcn_s_setprio(0);
  }

  // epilogue: reduce l across quads, normalize, pack, transpose via LDS
  __syncthreads();
  ushort_t* sm = &smem[0][0];
  {
    float l0 = l_run;
    l0 += __shfl_xor(l0, 16);
    l0 += __shfl_xor(l0, 32);
    float inv_l = 1.0f / l0;
    int row = wave * 16 + l16;  // 0..63
#pragma unroll
    for (int db = 0; db < 4; ++db) {
#pragma unroll
      for (int rr = 0; rr < 2; ++rr) {
        unsigned pk = pack2bf(oacc[db][rr * 2] * inv_l, oacc[db][rr * 2 + 1] * inv_l);
        *(unsigned*)(sm + row * 72 + db * 16 + quad * 4 + rr * 2) = pk;
      }
    }
  }
  __syncthreads();
  {
    int r = tid >> 2, c = (tid & 3) * 16;
    const ushort_t* src = sm + r * 72 + c;
    ushort_t* dst = O + ((size_t)b * S_ + q0 + r) * D_ + hoff + c;
    uint4 v0 = *(const uint4*)(src);
    uint4 v1 = *(const uint4*)(src + 8);
    *(uint4*)(dst) = v0;
    *(uint4*)(dst + 8) = v1;
  }
}

// ---------------------------------------------------------------------------
extern "C" void kernel_launch(void* const* d_in, const int* in_sizes, int n_in,
                              void* d_out, int out_size, void* d_ws, size_t ws_size,
                              hipStream_t stream) {
  (void)in_sizes; (void)n_in; (void)out_size; (void)ws_size;
  char* ws = (char*)d_ws;
  ushort_t* xq = (ushort_t*)(ws + 0);
  ushort_t* xk = (ushort_t*)(ws + 8388608);
  ushort_t* xv = (ushort_t*)(ws + 16777216);
  ushort_t* wq = (ushort_t*)(ws + 25165824);
  ushort_t* wk = (ushort_t*)(ws + 27262976);
  ushort_t* wv = (ushort_t*)(ws + 29360128);
  ushort_t* wo = (ushort_t*)(ws + 31457280);
  ushort_t* Qp = (ushort_t*)(ws + 33554432);
  ushort_t* Kp = (ushort_t*)(ws + 41943040);
  ushort_t* Vt = (ushort_t*)(ws + 50331648);  // V GEMM writes transposed here
  ushort_t* O = xq;   // xq dead after QKV GEMM

  ConvArgs ca;
  ca.src[0] = (const float*)d_in[0];  ca.dst[0] = xq;
  ca.src[1] = (const float*)d_in[1];  ca.dst[1] = xk;
  ca.src[2] = (const float*)d_in[2];  ca.dst[2] = xv;
  ca.src[3] = (const float*)d_in[4];  ca.dst[3] = wq;
  ca.src[4] = (const float*)d_in[6];  ca.dst[4] = wk;
  ca.src[5] = (const float*)d_in[8];  ca.dst[5] = wv;
  ca.src[6] = (const float*)d_in[10]; ca.dst[6] = wo;
  convert_kernel<<<dim3(4096), dim3(256), 0, stream>>>(ca);

  QkvArgs qa;
  qa.A[0] = xq; qa.W[0] = wq; qa.bias[0] = (const float*)d_in[5]; qa.out[0] = Qp;
  qa.A[1] = xk; qa.W[1] = wk; qa.bias[1] = (const float*)d_in[7]; qa.out[1] = Kp;
  qa.A[2] = xv; qa.W[2] = wv; qa.bias[2] = (const float*)d_in[9]; qa.out[2] = Vt;
  qa.scale[0] = 0.125f * 1.44269504089f;  // fold 1/sqrt(dk) * log2(e) into Q
  qa.scale[1] = 1.0f;
  qa.scale[2] = 1.0f;
  gemm_qkv_kernel<<<dim3(8, 64, 3), dim3(256), 0, stream>>>(qa);

  attn_kernel<<<dim3(1024), dim3(256), 0, stream>>>(Qp, Kp, Vt, O);

  gemm_out_kernel<<<dim3(8, 64, 1), dim3(256), 0, stream>>>(
      O, wo, (const float*)d_in[11], (float*)d_out);
}

// Round 8
// 222.989 us; speedup vs baseline: 1.0220x; 1.0220x over previous
//
#include <hip/hip_runtime.h>
#include <hip/hip_bf16.h>
#include <stdint.h>

#define B_ 2
#define S_ 2048
#define D_ 1024
#define H_ 16
#define DK_ 64

typedef __attribute__((ext_vector_type(4))) float floatx4;
typedef __attribute__((ext_vector_type(8))) short shortx8;
typedef __attribute__((ext_vector_type(4))) short shortx4;
typedef unsigned short ushort_t;

// f32 -> bf16 round-to-nearest-even (used for GEMM outputs)
__device__ inline ushort_t f2bf(float f) {
  union { float f; unsigned u; } v; v.f = f;
  unsigned r = v.u + 0x7FFFu + ((v.u >> 16) & 1u);
  return (ushort_t)(r >> 16);
}

// pack two f32 -> bf16x2 by truncation (1 v_perm); fine for P >= 0 / O
__device__ inline unsigned pack2bf(float lo, float hi) {
  return __builtin_amdgcn_perm(__float_as_uint(hi), __float_as_uint(lo), 0x07060302u);
}

__device__ inline shortx4 mk_sx4(unsigned lo, unsigned hi) {
  union { unsigned u[2]; shortx4 s; } v; v.u[0] = lo; v.u[1] = hi; return v.s;
}

// concat two shortx4 -> shortx8 (register-only)
__device__ inline shortx8 cat44(shortx4 a, shortx4 b) {
  union { shortx4 s4[2]; shortx8 s8; } v; v.s4[0] = a; v.s4[1] = b; return v.s8;
}

__device__ inline float fast_exp2(float x) {
#if __has_builtin(__builtin_amdgcn_exp2f)
  return __builtin_amdgcn_exp2f(x);
#else
  return __expf(0.69314718056f * x);
#endif
}

__device__ inline void gload_lds16(const void* g, void* l) {
  __builtin_amdgcn_global_load_lds(
      (const __attribute__((address_space(1))) unsigned int*)g,
      (__attribute__((address_space(3))) unsigned int*)l, 16, 0, 0);
}

// ---------------- fp32 -> bf16 conversion (7 tensors fused) ----------------
// Round-8 failure: fusing into the GEMM via global->VGPR->ds_write serialized
// (no async queue). Round-13 failure: staging f32 A directly doubled staging
// bytes + cvt VALU and conflicted anyway (43->82 us). Conversion stays
// standalone (pure-BW, ~23 us at 4.9 TB/s effective).
struct ConvArgs {
  const float* src[7];
  ushort_t* dst[7];
};

__global__ __launch_bounds__(256) void convert_kernel(ConvArgs a) {
  int blk = blockIdx.x;
  int seg, bis;
  if (blk < 3072) { seg = blk >> 10; bis = blk & 1023; }
  else { int bb = blk - 3072; seg = 3 + (bb >> 8); bis = bb & 255; }
  const float4* src = (const float4*)(a.src[seg]) + (size_t)bis * 1024;
  ushort4* dst = (ushort4*)(a.dst[seg]) + (size_t)bis * 1024;
#pragma unroll
  for (int i = 0; i < 4; ++i) {
    int idx = i * 256 + threadIdx.x;
    float4 v = src[idx];
    ushort4 o;
    o.x = f2bf(v.x); o.y = f2bf(v.y); o.z = f2bf(v.z); o.w = f2bf(v.w);
    dst[idx] = o;
  }
}

// ---------------- GEMM: C[m][n] = (sum_k A[m][k]*W[n][k] + bias[n])*scl ----
// 2-phase schedule + BK=64, 128B rows, 8-chunk XOR swizzle (stored chunk =
// logical ^ (row&7); pre-swizzled global source, linear gload_lds dest,
// XOR'd ds_read). Conflict-free (R1/R5/R6 counter-proven). TM=64 -> 48KB
// LDS, 3 blocks/CU (R7: Occ 25%, MfmaUtil 24%).
// R7 PLATEAU NOTE: dur x MfmaUtil = 9.9 us == the 25.8 GF compute floor ->
// MFMA pipe time is AT floor; remaining 75% is exposed wait that neither
// 8-phase scheduling (R1/R2: 94/62 us) nor tile/occupancy moves (R0-R7)
// recovered. Do not re-attempt without a fundamentally new mechanism.
// outmode: 0 = bf16 row-major, 1 = f32 row-major,
//          2 = bf16 V-transpose out[(b*1024+n)*2048 + s], m = b*2048+s.
template <int TM>
__device__ inline void gemm_bk64_core(const ushort_t* __restrict__ A,
                                      const ushort_t* __restrict__ W,
                                      const float* __restrict__ bias,
                                      float scl,
                                      void* __restrict__ outp,
                                      int m0, int n0, int N, int K, int outmode) {
  constexpr int GA = TM / 8;        // A gloads (8 rows of 128B each)
  constexpr int GB = 16;            // B gloads (128 rows)
  constexpr int GW = (GA + GB) / 4; // gloads per wave
  constexpr int MI = TM / 32;       // m-frags per wave
  constexpr int BUFB = (TM + 128) * 128;  // bytes per buffer
  __shared__ uint4 smem4[2 * BUFB / 16];
  char* smem = (char*)&smem4[0];

  const int tid = threadIdx.x;
  const int wave = tid >> 6;
  const int lane = tid & 63;
  const int quad = lane >> 4;
  const int l16 = lane & 15;
  const int wm = (wave >> 1) * (TM / 2);
  const int wn = (wave & 1) * 64;

  floatx4 acc[MI][4] = {};

  // staging: gload g covers 8 rows x 128B; lane -> row g*8+(lane>>3),
  // stored chunk (lane&7) holds global chunk (lane&7)^(lane>>3).
  const ushort_t* gsrc[GW];
  int ldst[GW];
#pragma unroll
  for (int i = 0; i < GW; ++i) {
    int g = wave * GW + i;
    int r8 = lane >> 3;
    int cs = ((lane & 7) ^ r8) * 8;  // ushort offset of swizzled source chunk
    if (g < GA) {
      gsrc[i] = A + (size_t)(m0 + g * 8 + r8) * K + cs;
      ldst[i] = g * 1024 + lane * 16;
    } else {
      gsrc[i] = W + (size_t)(n0 + (g - GA) * 8 + r8) * K + cs;
      ldst[i] = TM * 128 + (g - GA) * 1024 + lane * 16;
    }
  }

#pragma unroll
  for (int i = 0; i < GW; ++i) gload_lds16(gsrc[i], smem + ldst[i]);

  const int niter = K >> 6;
  for (int j = 0; j < niter; ++j) {
    __syncthreads();
    if (j + 1 < niter) {
      const int ko = (j + 1) * 64;
      char* bufn = smem + ((j + 1) & 1) * BUFB;
#pragma unroll
      for (int i = 0; i < GW; ++i) gload_lds16(gsrc[i] + ko, bufn + ldst[i]);
    }
    const char* aT = smem + (j & 1) * BUFB;
    const char* bT = aT + TM * 128;
    // frag reads: row r at byte r*128; k-step ks chunk (ks*4+quad)^(r&7).
    shortx8 af[MI][2], bf[4][2];
#pragma unroll
    for (int ks = 0; ks < 2; ++ks) {
      const int co = ((ks * 4 + quad) ^ (l16 & 7)) * 16;
#pragma unroll
      for (int mi = 0; mi < MI; ++mi)
        af[mi][ks] = *(const shortx8*)(aT + (wm + mi * 16 + l16) * 128 + co);
#pragma unroll
      for (int ni = 0; ni < 4; ++ni)
        bf[ni][ks] = *(const shortx8*)(bT + (wn + ni * 16 + l16) * 128 + co);
    }
#pragma unroll
    for (int ks = 0; ks < 2; ++ks)
#pragma unroll
      for (int mi = 0; mi < MI; ++mi)
#pragma unroll
        for (int ni = 0; ni < 4; ++ni)
          acc[mi][ni] = __builtin_amdgcn_mfma_f32_16x16x32_bf16(af[mi][ks], bf[ni][ks], acc[mi][ni], 0, 0, 0);
  }

  // epilogue: C/D layout col=lane&15, row=quad*4+r
#pragma unroll
  for (int ni = 0; ni < 4; ++ni) {
    int n = n0 + wn + ni * 16 + l16;
    float bv = bias[n];
#pragma unroll
    for (int mi = 0; mi < MI; ++mi) {
      if (outmode == 2) {
        int m = m0 + wm + mi * 16 + quad * 4;
        int b = m >> 11, s = m & 2047;
        ushort_t* dst = (ushort_t*)outp + (((size_t)(b * 1024 + n)) << 11) + s;
        uint2 pk;
        pk.x = (unsigned)f2bf(acc[mi][ni][0] + bv) |
               ((unsigned)f2bf(acc[mi][ni][1] + bv) << 16);
        pk.y = (unsigned)f2bf(acc[mi][ni][2] + bv) |
               ((unsigned)f2bf(acc[mi][ni][3] + bv) << 16);
        *(uint2*)(dst) = pk;  // single 8B store (8B-aligned: s = quad*4)
      } else {
#pragma unroll
        for (int r = 0; r < 4; ++r) {
          int m = m0 + wm + mi * 16 + quad * 4 + r;
          float v = (acc[mi][ni][r] + bv) * scl;
          if (outmode == 1) ((float*)outp)[(size_t)m * N + n] = v;
          else ((ushort_t*)outp)[(size_t)m * N + n] = f2bf(v);
        }
      }
    }
  }
}

struct QkvArgs {
  const ushort_t* A[3];
  const ushort_t* W[3];
  const float* bias[3];
  ushort_t* out[3];
  float scale[3];
};

// grid (8,64,3), TM=64 tiles (48KB LDS -> 3 blocks/CU, 12 waves).
// XCD swizzle: flat%8 == blockIdx.x -> XCD c's working set = 512 A-rows
// (1MB) + full W (2MB) < 4MB L2.
// z==2 (V) writes the transposed layout consumed by attention (fused vtrans).
__global__ __launch_bounds__(256) void gemm_qkv_kernel(QkvArgs a) {
  int z = blockIdx.z;
  int m0 = (blockIdx.x * 8 + (blockIdx.y >> 3)) * 64;
  int n0 = (blockIdx.y & 7) * 128;
  gemm_bk64_core<64>(a.A[z], a.W[z], a.bias[z], a.scale[z], a.out[z],
                     m0, n0, D_, D_, z == 2 ? 2 : 0);
}

// grid (8,64); 64x128 tiles, same swizzle principle.
__global__ __launch_bounds__(256) void gemm_out_kernel(const ushort_t* __restrict__ A,
                                                       const ushort_t* __restrict__ W,
                                                       const float* __restrict__ bias,
                                                       float* __restrict__ out) {
  int m0 = (blockIdx.x * 8 + (blockIdx.y >> 3)) * 64;
  int n0 = (blockIdx.y & 7) * 128;
  gemm_bk64_core<64>(A, W, bias, 1.0f, out, m0, n0, D_, D_, 1);
}

// ---------------- flash attention (causal), round 17 -----------------------
// Structure (validated R6): QBLK=64 (1 q-group/wave), K-tile 64, LDS 32KB ->
// 1024 blocks = 4/CU. Depth map: CU c's 4 ids have depths summing to a
// CONSTANT 66. 8-chunk XOR swizzle on K and V (conflict-free, counter-
// proven). setprio (T5) around MFMA clusters.
// Round 17: PV upgraded 16 x mfma_16x16x16 -> 8 x mfma_16x16x32 per tile.
// Legality: MFMA's reduction index is an internal slot enumeration; any
// slot->kk bijection works if A and B agree. Slot s = quad*8+i maps to
// kk = (i<4 ? k0 : k1)*16 + quad*4 + (i&3) for the kkb pair (k0,k1) --
// exactly the kk values this lane already holds in pf[k0],pf[k1] and
// already reads as vf(k0),vf(k1). Concatenate both operand pairs into
// shortx8 -> same data, same LDS reads, half the MFMA issue slots.
// (PV was ~17 us of x16 pipe time; x32 halves it.)
__global__ __launch_bounds__(256, 4) void attn_kernel(const ushort_t* __restrict__ Qp,
                                                      const ushort_t* __restrict__ Kp,
                                                      const ushort_t* __restrict__ Vt,
                                                      ushort_t* __restrict__ O) {
  const int id = blockIdx.x;
  const int h = id & 15;
  const int u = (id >> 4) & 31;
  const int b = id >> 9;
  const int qt = b ? u : 31 - u;
  const int q0 = qt * 64;
  const int tid = threadIdx.x;
  const int wave = tid >> 6;
  const int lane = tid & 63;
  const int quad = lane >> 4;
  const int l16 = lane & 15;

  __shared__ ushort_t smem[2][8192];  // per buf: K[64][64] | V^T[64][64] = 16KB

  const size_t hoff = (size_t)h * DK_;

  // Q B-frags: lane holds Q[q=l16][d=ks*32+quad*8+i] (already exp2-scaled)
  shortx8 qf[2];
  {
    const ushort_t* qrow = Qp + ((size_t)b * S_ + q0 + wave * 16 + l16) * D_ + hoff;
    qf[0] = *(const shortx8*)(qrow + quad * 8);
    qf[1] = *(const shortx8*)(qrow + 32 + quad * 8);
  }

  // staging: per wave 2 K-gloads + 2 V-gloads, 8 rows x 8 chunks each;
  // stored chunk (lane&7) holds global chunk (lane&7)^(lane>>3).
  const int r8 = lane >> 3;
  const int cs8 = ((lane & 7) ^ r8) * 8;  // swizzled source chunk (ushorts)
  const ushort_t* kb[2];
  const ushort_t* vb[2];
  int kdst[2], vdst[2];
#pragma unroll
  for (int g = 0; g < 2; ++g) {
    const int tr = wave * 16 + g * 8 + r8;  // tile row 0..63
    kb[g] = Kp + ((size_t)b * S_ + tr) * D_ + hoff + cs8;
    vb[g] = Vt + ((size_t)(b * H_ + h) * 64 + tr) * (size_t)S_ + cs8;
    kdst[g] = (wave * 16 + g * 8) * 64 + lane * 8;         // ushort index
    vdst[g] = 4096 + (wave * 16 + g * 8) * 64 + lane * 8;
  }

  floatx4 oacc[4] = {};
  float l_run = 0.f;
  const int nj = qt + 1;

  // preload tile 0 into buffer 0
#pragma unroll
  for (int g = 0; g < 2; ++g) {
    gload_lds16(kb[g], &smem[0][kdst[g]]);
    gload_lds16(vb[g], &smem[0][vdst[g]]);
  }

  for (int j = 0; j < nj; ++j) {
    __syncthreads();
    if (j + 1 < nj) {
      ushort_t* bufn = smem[(j + 1) & 1];
      const size_t ko = (size_t)(j + 1) * 64 * D_;  // 64 k-rows ahead
      const int vo = (j + 1) * 64;                  // 64 k-cols ahead
#pragma unroll
      for (int g = 0; g < 2; ++g) {
        gload_lds16(kb[g] + ko, bufn + kdst[g]);
        gload_lds16(vb[g] + vo, bufn + vdst[g]);
      }
    }
    const ushort_t* k_lds = smem[j & 1];
    const ushort_t* v_lds = smem[j & 1] + 4096;

    // QK^T: S^T[kk=kkb*16+quad*4+r][q=l16]
    floatx4 sacc[4];
    __builtin_amdgcn_s_setprio(1);
#pragma unroll
    for (int kkb = 0; kkb < 4; ++kkb) {
      const ushort_t* krow = k_lds + (kkb * 16 + l16) * 64;
      shortx8 af0 = *(const shortx8*)(krow + (quad ^ (l16 & 7)) * 8);
      shortx8 af1 = *(const shortx8*)(krow + ((4 | quad) ^ (l16 & 7)) * 8);
      floatx4 acc = {0.f, 0.f, 0.f, 0.f};
      acc = __builtin_amdgcn_mfma_f32_16x16x32_bf16(af0, qf[0], acc, 0, 0, 0);
      acc = __builtin_amdgcn_mfma_f32_16x16x32_bf16(af1, qf[1], acc, 0, 0, 0);
      sacc[kkb] = acc;
    }
    __builtin_amdgcn_s_setprio(0);

    // diagonal masking (only the last tile can cross the diagonal)
    const int kbase = j * 64;
    if (kbase + 63 > q0 + wave * 16) {
      const int qg = q0 + wave * 16 + l16;
#pragma unroll
      for (int kkb = 0; kkb < 4; ++kkb)
#pragma unroll
        for (int r = 0; r < 4; ++r)
          if (kbase + kkb * 16 + quad * 4 + r > qg) sacc[kkb][r] = -3.0e38f;
    }

    // no-max softmax: p = exp2(s); per-lane partial l
    shortx4 pf[4];
    {
      float psum = 0.f;
#pragma unroll
      for (int kkb = 0; kkb < 4; ++kkb) {
        float p0 = fast_exp2(sacc[kkb][0]);
        float p1 = fast_exp2(sacc[kkb][1]);
        float p2 = fast_exp2(sacc[kkb][2]);
        float p3 = fast_exp2(sacc[kkb][3]);
        psum += (p0 + p1) + (p2 + p3);
        pf[kkb] = mk_sx4(pack2bf(p0, p1), pack2bf(p2, p3));
      }
      l_run += psum;
    }

    // PV (x32 form): for kkb pair (k0,k1), slot s=quad*8+i <-> kk =
    // (i<4?k0:k1)*16 + quad*4 + (i&3). A = V^T[d][kk(s)] = vf(k0)++vf(k1);
    // B = P[kk(s)][q] = pf[k0]++pf[k1]. V chunk (kkb*2+(quad>>1))^(l16&7),
    // (quad&1) picks the 8B half -> 2-way max (free).
    __builtin_amdgcn_s_setprio(1);
#pragma unroll
    for (int kp = 0; kp < 2; ++kp) {
      const int k0 = kp * 2, k1 = kp * 2 + 1;
      const shortx8 pf8 = cat44(pf[k0], pf[k1]);
      const int jj0 = ((k0 * 2 + (quad >> 1)) ^ (l16 & 7)) * 8 + (quad & 1) * 4;
      const int jj1 = ((k1 * 2 + (quad >> 1)) ^ (l16 & 7)) * 8 + (quad & 1) * 4;
#pragma unroll
      for (int db = 0; db < 4; ++db) {
        const ushort_t* vrow = v_lds + (db * 16 + l16) * 64;
        shortx8 vf8 = cat44(*(const shortx4*)(vrow + jj0),
                            *(const shortx4*)(vrow + jj1));
        oacc[db] = __builtin_amdgcn_mfma_f32_16x16x32_bf16(vf8, pf8, oacc[db], 0, 0, 0);
      }
    }
    __builtin_amdgcn_s_setprio(0);
  }

  // epilogue: reduce l across quads, normalize, pack, transpose via LDS
  __syncthreads();
  ushort_t* sm = &smem[0][0];
  {
    float l0 = l_run;
    l0 += __shfl_xor(l0, 16);
    l0 += __shfl_xor(l0, 32);
    float inv_l = 1.0f / l0;
    int row = wave * 16 + l16;  // 0..63
#pragma unroll
    for (int db = 0; db < 4; ++db) {
#pragma unroll
      for (int rr = 0; rr < 2; ++rr) {
        unsigned pk = pack2bf(oacc[db][rr * 2] * inv_l, oacc[db][rr * 2 + 1] * inv_l);
        *(unsigned*)(sm + row * 72 + db * 16 + quad * 4 + rr * 2) = pk;
      }
    }
  }
  __syncthreads();
  {
    int r = tid >> 2, c = (tid & 3) * 16;
    const ushort_t* src = sm + r * 72 + c;
    ushort_t* dst = O + ((size_t)b * S_ + q0 + r) * D_ + hoff + c;
    uint4 v0 = *(const uint4*)(src);
    uint4 v1 = *(const uint4*)(src + 8);
    *(uint4*)(dst) = v0;
    *(uint4*)(dst + 8) = v1;
  }
}

// ---------------------------------------------------------------------------
extern "C" void kernel_launch(void* const* d_in, const int* in_sizes, int n_in,
                              void* d_out, int out_size, void* d_ws, size_t ws_size,
                              hipStream_t stream) {
  (void)in_sizes; (void)n_in; (void)out_size; (void)ws_size;
  char* ws = (char*)d_ws;
  ushort_t* xq = (ushort_t*)(ws + 0);
  ushort_t* xk = (ushort_t*)(ws + 8388608);
  ushort_t* xv = (ushort_t*)(ws + 16777216);
  ushort_t* wq = (ushort_t*)(ws + 25165824);
  ushort_t* wk = (ushort_t*)(ws + 27262976);
  ushort_t* wv = (ushort_t*)(ws + 29360128);
  ushort_t* wo = (ushort_t*)(ws + 31457280);
  ushort_t* Qp = (ushort_t*)(ws + 33554432);
  ushort_t* Kp = (ushort_t*)(ws + 41943040);
  ushort_t* Vt = (ushort_t*)(ws + 50331648);  // V GEMM writes transposed here
  ushort_t* O = xq;   // xq dead after QKV GEMM

  ConvArgs ca;
  ca.src[0] = (const float*)d_in[0];  ca.dst[0] = xq;
  ca.src[1] = (const float*)d_in[1];  ca.dst[1] = xk;
  ca.src[2] = (const float*)d_in[2];  ca.dst[2] = xv;
  ca.src[3] = (const float*)d_in[4];  ca.dst[3] = wq;
  ca.src[4] = (const float*)d_in[6];  ca.dst[4] = wk;
  ca.src[5] = (const float*)d_in[8];  ca.dst[5] = wv;
  ca.src[6] = (const float*)d_in[10]; ca.dst[6] = wo;
  convert_kernel<<<dim3(4096), dim3(256), 0, stream>>>(ca);

  QkvArgs qa;
  qa.A[0] = xq; qa.W[0] = wq; qa.bias[0] = (const float*)d_in[5]; qa.out[0] = Qp;
  qa.A[1] = xk; qa.W[1] = wk; qa.bias[1] = (const float*)d_in[7]; qa.out[1] = Kp;
  qa.A[2] = xv; qa.W[2] = wv; qa.bias[2] = (const float*)d_in[9]; qa.out[2] = Vt;
  qa.scale[0] = 0.125f * 1.44269504089f;  // fold 1/sqrt(dk) * log2(e) into Q
  qa.scale[1] = 1.0f;
  qa.scale[2] = 1.0f;
  gemm_qkv_kernel<<<dim3(8, 64, 3), dim3(256), 0, stream>>>(qa);

  attn_kernel<<<dim3(1024), dim3(256), 0, stream>>>(Qp, Kp, Vt, O);

  gemm_out_kernel<<<dim3(8, 64, 1), dim3(256), 0, stream>>>(
      O, wo, (const float*)d_in[11], (float*)d_out);
}

// Round 9
// 217.358 us; speedup vs baseline: 1.0485x; 1.0259x over previous
//
#include <hip/hip_runtime.h>
#include <hip/hip_bf16.h>
#include <stdint.h>

#define B_ 2
#define S_ 2048
#define D_ 1024
#define H_ 16
#define DK_ 64

typedef __attribute__((ext_vector_type(4))) float floatx4;
typedef __attribute__((ext_vector_type(8))) short shortx8;
typedef __attribute__((ext_vector_type(4))) short shortx4;
typedef unsigned short ushort_t;

// f32 -> bf16 round-to-nearest-even (used for GEMM outputs)
__device__ inline ushort_t f2bf(float f) {
  union { float f; unsigned u; } v; v.f = f;
  unsigned r = v.u + 0x7FFFu + ((v.u >> 16) & 1u);
  return (ushort_t)(r >> 16);
}

// pack two f32 -> bf16x2 by truncation (1 v_perm); fine for P >= 0 / O
__device__ inline unsigned pack2bf(float lo, float hi) {
  return __builtin_amdgcn_perm(__float_as_uint(hi), __float_as_uint(lo), 0x07060302u);
}

__device__ inline shortx4 mk_sx4(unsigned lo, unsigned hi) {
  union { unsigned u[2]; shortx4 s; } v; v.u[0] = lo; v.u[1] = hi; return v.s;
}

// concat two shortx4 -> shortx8 (register-only)
__device__ inline shortx8 cat44(shortx4 a, shortx4 b) {
  union { shortx4 s4[2]; shortx8 s8; } v; v.s4[0] = a; v.s4[1] = b; return v.s8;
}

__device__ inline float fast_exp2(float x) {
#if __has_builtin(__builtin_amdgcn_exp2f)
  return __builtin_amdgcn_exp2f(x);
#else
  return __expf(0.69314718056f * x);
#endif
}

__device__ inline void gload_lds16(const void* g, void* l) {
  __builtin_amdgcn_global_load_lds(
      (const __attribute__((address_space(1))) unsigned int*)g,
      (__attribute__((address_space(3))) unsigned int*)l, 16, 0, 0);
}

// ---------------- fp32 -> bf16 conversion (7 tensors fused) ----------------
// Round-8 failure: fusing into the GEMM via global->VGPR->ds_write serialized
// (no async queue). Round-13 failure: staging f32 A directly doubled staging
// bytes + cvt VALU and conflicted anyway (43->82 us). Conversion stays
// standalone (pure-BW, ~23 us at 4.9 TB/s effective).
struct ConvArgs {
  const float* src[7];
  ushort_t* dst[7];
};

__global__ __launch_bounds__(256) void convert_kernel(ConvArgs a) {
  int blk = blockIdx.x;
  int seg, bis;
  if (blk < 3072) { seg = blk >> 10; bis = blk & 1023; }
  else { int bb = blk - 3072; seg = 3 + (bb >> 8); bis = bb & 255; }
  const float4* src = (const float4*)(a.src[seg]) + (size_t)bis * 1024;
  ushort4* dst = (ushort4*)(a.dst[seg]) + (size_t)bis * 1024;
#pragma unroll
  for (int i = 0; i < 4; ++i) {
    int idx = i * 256 + threadIdx.x;
    float4 v = src[idx];
    ushort4 o;
    o.x = f2bf(v.x); o.y = f2bf(v.y); o.z = f2bf(v.z); o.w = f2bf(v.w);
    dst[idx] = o;
  }
}

// ---------------- GEMM: C[m][n] = (sum_k A[m][k]*W[n][k] + bias[n])*scl ----
// 2-phase schedule + BK=64, 128B rows, 8-chunk XOR swizzle (stored chunk =
// logical ^ (row&7); pre-swizzled global source, linear gload_lds dest,
// XOR'd ds_read). Conflict-free (R1/R5/R6 counter-proven). TM=64 -> 48KB
// LDS, 3 blocks/CU (R7: Occ 25%, MfmaUtil 24%).
// R7 PLATEAU NOTE: dur x MfmaUtil = 9.9 us == the 25.8 GF compute floor ->
// MFMA pipe time is AT floor; remaining 75% is exposed wait that neither
// 8-phase scheduling (R1/R2: 94/62 us) nor tile/occupancy moves (R0-R7)
// recovered. Do not re-attempt without a fundamentally new mechanism.
// outmode: 0 = bf16 row-major, 1 = f32 row-major,
//          2 = bf16 V-transpose out[(b*1024+n)*2048 + s'] with the round-18
//              PV-pair permutation: s' = (s & ~31) | (quad*8 + mi*4) + r.
//              Within each 32-s half-tile, the 8B unit at logical
//              u = 4k+quad (k = kkb parity, from mi) is stored at
//              u' = 2*quad + k -> attn's PV lane reads ONE contiguous 16B
//              chunk c = 4*kp+quad per kkb-pair = the proven conflict-free
//              b128 pattern (R8: b64 form measured 4.42M conflict-cycles
//              = 4 cyc/read; b128 GEMM form measures 0).
template <int TM>
__device__ inline void gemm_bk64_core(const ushort_t* __restrict__ A,
                                      const ushort_t* __restrict__ W,
                                      const float* __restrict__ bias,
                                      float scl,
                                      void* __restrict__ outp,
                                      int m0, int n0, int N, int K, int outmode) {
  constexpr int GA = TM / 8;        // A gloads (8 rows of 128B each)
  constexpr int GB = 16;            // B gloads (128 rows)
  constexpr int GW = (GA + GB) / 4; // gloads per wave
  constexpr int MI = TM / 32;       // m-frags per wave
  constexpr int BUFB = (TM + 128) * 128;  // bytes per buffer
  __shared__ uint4 smem4[2 * BUFB / 16];
  char* smem = (char*)&smem4[0];

  const int tid = threadIdx.x;
  const int wave = tid >> 6;
  const int lane = tid & 63;
  const int quad = lane >> 4;
  const int l16 = lane & 15;
  const int wm = (wave >> 1) * (TM / 2);
  const int wn = (wave & 1) * 64;

  floatx4 acc[MI][4] = {};

  // staging: gload g covers 8 rows x 128B; lane -> row g*8+(lane>>3),
  // stored chunk (lane&7) holds global chunk (lane&7)^(lane>>3).
  const ushort_t* gsrc[GW];
  int ldst[GW];
#pragma unroll
  for (int i = 0; i < GW; ++i) {
    int g = wave * GW + i;
    int r8 = lane >> 3;
    int cs = ((lane & 7) ^ r8) * 8;  // ushort offset of swizzled source chunk
    if (g < GA) {
      gsrc[i] = A + (size_t)(m0 + g * 8 + r8) * K + cs;
      ldst[i] = g * 1024 + lane * 16;
    } else {
      gsrc[i] = W + (size_t)(n0 + (g - GA) * 8 + r8) * K + cs;
      ldst[i] = TM * 128 + (g - GA) * 1024 + lane * 16;
    }
  }

#pragma unroll
  for (int i = 0; i < GW; ++i) gload_lds16(gsrc[i], smem + ldst[i]);

  const int niter = K >> 6;
  for (int j = 0; j < niter; ++j) {
    __syncthreads();
    if (j + 1 < niter) {
      const int ko = (j + 1) * 64;
      char* bufn = smem + ((j + 1) & 1) * BUFB;
#pragma unroll
      for (int i = 0; i < GW; ++i) gload_lds16(gsrc[i] + ko, bufn + ldst[i]);
    }
    const char* aT = smem + (j & 1) * BUFB;
    const char* bT = aT + TM * 128;
    // frag reads: row r at byte r*128; k-step ks chunk (ks*4+quad)^(r&7).
    shortx8 af[MI][2], bf[4][2];
#pragma unroll
    for (int ks = 0; ks < 2; ++ks) {
      const int co = ((ks * 4 + quad) ^ (l16 & 7)) * 16;
#pragma unroll
      for (int mi = 0; mi < MI; ++mi)
        af[mi][ks] = *(const shortx8*)(aT + (wm + mi * 16 + l16) * 128 + co);
#pragma unroll
      for (int ni = 0; ni < 4; ++ni)
        bf[ni][ks] = *(const shortx8*)(bT + (wn + ni * 16 + l16) * 128 + co);
    }
#pragma unroll
    for (int ks = 0; ks < 2; ++ks)
#pragma unroll
      for (int mi = 0; mi < MI; ++mi)
#pragma unroll
        for (int ni = 0; ni < 4; ++ni)
          acc[mi][ni] = __builtin_amdgcn_mfma_f32_16x16x32_bf16(af[mi][ks], bf[ni][ks], acc[mi][ni], 0, 0, 0);
  }

  // epilogue: C/D layout col=lane&15, row=quad*4+r
#pragma unroll
  for (int ni = 0; ni < 4; ++ni) {
    int n = n0 + wn + ni * 16 + l16;
    float bv = bias[n];
#pragma unroll
    for (int mi = 0; mi < MI; ++mi) {
      if (outmode == 2) {
        int m = m0 + wm + mi * 16 + quad * 4;
        int b = m >> 11;
        // round-18 PV-pair permutation (see header comment)
        int s = (m & 2047 & ~31) | (quad * 8 + mi * 4);
        ushort_t* dst = (ushort_t*)outp + (((size_t)(b * 1024 + n)) << 11) + s;
        uint2 pk;
        pk.x = (unsigned)f2bf(acc[mi][ni][0] + bv) |
               ((unsigned)f2bf(acc[mi][ni][1] + bv) << 16);
        pk.y = (unsigned)f2bf(acc[mi][ni][2] + bv) |
               ((unsigned)f2bf(acc[mi][ni][3] + bv) << 16);
        *(uint2*)(dst) = pk;  // single 8B store (8B-aligned)
      } else {
#pragma unroll
        for (int r = 0; r < 4; ++r) {
          int m = m0 + wm + mi * 16 + quad * 4 + r;
          float v = (acc[mi][ni][r] + bv) * scl;
          if (outmode == 1) ((float*)outp)[(size_t)m * N + n] = v;
          else ((ushort_t*)outp)[(size_t)m * N + n] = f2bf(v);
        }
      }
    }
  }
}

struct QkvArgs {
  const ushort_t* A[3];
  const ushort_t* W[3];
  const float* bias[3];
  ushort_t* out[3];
  float scale[3];
};

// grid (8,64,3), TM=64 tiles (48KB LDS -> 3 blocks/CU, 12 waves).
// XCD swizzle: flat%8 == blockIdx.x -> XCD c's working set = 512 A-rows
// (1MB) + full W (2MB) < 4MB L2.
// z==2 (V) writes the transposed+permuted layout consumed by attention.
__global__ __launch_bounds__(256) void gemm_qkv_kernel(QkvArgs a) {
  int z = blockIdx.z;
  int m0 = (blockIdx.x * 8 + (blockIdx.y >> 3)) * 64;
  int n0 = (blockIdx.y & 7) * 128;
  gemm_bk64_core<64>(a.A[z], a.W[z], a.bias[z], a.scale[z], a.out[z],
                     m0, n0, D_, D_, z == 2 ? 2 : 0);
}

// grid (8,64); 64x128 tiles, same swizzle principle.
__global__ __launch_bounds__(256) void gemm_out_kernel(const ushort_t* __restrict__ A,
                                                       const ushort_t* __restrict__ W,
                                                       const float* __restrict__ bias,
                                                       float* __restrict__ out) {
  int m0 = (blockIdx.x * 8 + (blockIdx.y >> 3)) * 64;
  int n0 = (blockIdx.y & 7) * 128;
  gemm_bk64_core<64>(A, W, bias, 1.0f, out, m0, n0, D_, D_, 1);
}

// ---------------- flash attention (causal), round 18 -----------------------
// Structure (validated R6): QBLK=64 (1 q-group/wave), K-tile 64, LDS 32KB ->
// 1024 blocks = 4/CU. Depth map: CU c's 4 ids have depths summing to a
// CONSTANT 66. 8-chunk XOR swizzle on K and V staging. setprio (T5).
// R8 counters: attn MFMA time (dur x MfmaUtil = 6.7us) == x32 compute floor;
// SQ_LDS_BANK_CONFLICT 4.42M == 4 cyc x 1.08M PV b64 reads (exact match).
// Round 18: Vt carries the PV-pair permutation (see gemm core header), so
// PV reads ONE b128 per (kp,db) at chunk (4kp+quad)^(l16&7) -- the pattern
// that measures 0 conflicts in the GEMMs -- and feeds mfma x32 directly:
// slots i<4 = kkb 2kp (r=0..3), i>=4 = kkb 2kp+1, matching
// cat44(pf[2kp], pf[2kp+1]). Read count halves (8 b128 vs 16 b64).
__global__ __launch_bounds__(256, 4) void attn_kernel(const ushort_t* __restrict__ Qp,
                                                      const ushort_t* __restrict__ Kp,
                                                      const ushort_t* __restrict__ Vt,
                                                      ushort_t* __restrict__ O) {
  const int id = blockIdx.x;
  const int h = id & 15;
  const int u = (id >> 4) & 31;
  const int b = id >> 9;
  const int qt = b ? u : 31 - u;
  const int q0 = qt * 64;
  const int tid = threadIdx.x;
  const int wave = tid >> 6;
  const int lane = tid & 63;
  const int quad = lane >> 4;
  const int l16 = lane & 15;

  __shared__ ushort_t smem[2][8192];  // per buf: K[64][64] | V^T[64][64] = 16KB

  const size_t hoff = (size_t)h * DK_;

  // Q B-frags: lane holds Q[q=l16][d=ks*32+quad*8+i] (already exp2-scaled)
  shortx8 qf[2];
  {
    const ushort_t* qrow = Qp + ((size_t)b * S_ + q0 + wave * 16 + l16) * D_ + hoff;
    qf[0] = *(const shortx8*)(qrow + quad * 8);
    qf[1] = *(const shortx8*)(qrow + 32 + quad * 8);
  }

  // staging: per wave 2 K-gloads + 2 V-gloads, 8 rows x 8 chunks each;
  // stored chunk (lane&7) holds global chunk (lane&7)^(lane>>3).
  const int r8 = lane >> 3;
  const int cs8 = ((lane & 7) ^ r8) * 8;  // swizzled source chunk (ushorts)
  const ushort_t* kb[2];
  const ushort_t* vb[2];
  int kdst[2], vdst[2];
#pragma unroll
  for (int g = 0; g < 2; ++g) {
    const int tr = wave * 16 + g * 8 + r8;  // tile row 0..63
    kb[g] = Kp + ((size_t)b * S_ + tr) * D_ + hoff + cs8;
    vb[g] = Vt + ((size_t)(b * H_ + h) * 64 + tr) * (size_t)S_ + cs8;
    kdst[g] = (wave * 16 + g * 8) * 64 + lane * 8;         // ushort index
    vdst[g] = 4096 + (wave * 16 + g * 8) * 64 + lane * 8;
  }

  floatx4 oacc[4] = {};
  float l_run = 0.f;
  const int nj = qt + 1;

  // preload tile 0 into buffer 0
#pragma unroll
  for (int g = 0; g < 2; ++g) {
    gload_lds16(kb[g], &smem[0][kdst[g]]);
    gload_lds16(vb[g], &smem[0][vdst[g]]);
  }

  for (int j = 0; j < nj; ++j) {
    __syncthreads();
    if (j + 1 < nj) {
      ushort_t* bufn = smem[(j + 1) & 1];
      const size_t ko = (size_t)(j + 1) * 64 * D_;  // 64 k-rows ahead
      const int vo = (j + 1) * 64;                  // 64 k-cols ahead
#pragma unroll
      for (int g = 0; g < 2; ++g) {
        gload_lds16(kb[g] + ko, bufn + kdst[g]);
        gload_lds16(vb[g] + vo, bufn + vdst[g]);
      }
    }
    const ushort_t* k_lds = smem[j & 1];
    const ushort_t* v_lds = smem[j & 1] + 4096;

    // QK^T: S^T[kk=kkb*16+quad*4+r][q=l16]
    floatx4 sacc[4];
    __builtin_amdgcn_s_setprio(1);
#pragma unroll
    for (int kkb = 0; kkb < 4; ++kkb) {
      const ushort_t* krow = k_lds + (kkb * 16 + l16) * 64;
      shortx8 af0 = *(const shortx8*)(krow + (quad ^ (l16 & 7)) * 8);
      shortx8 af1 = *(const shortx8*)(krow + ((4 | quad) ^ (l16 & 7)) * 8);
      floatx4 acc = {0.f, 0.f, 0.f, 0.f};
      acc = __builtin_amdgcn_mfma_f32_16x16x32_bf16(af0, qf[0], acc, 0, 0, 0);
      acc = __builtin_amdgcn_mfma_f32_16x16x32_bf16(af1, qf[1], acc, 0, 0, 0);
      sacc[kkb] = acc;
    }
    __builtin_amdgcn_s_setprio(0);

    // diagonal masking (only the last tile can cross the diagonal)
    const int kbase = j * 64;
    if (kbase + 63 > q0 + wave * 16) {
      const int qg = q0 + wave * 16 + l16;
#pragma unroll
      for (int kkb = 0; kkb < 4; ++kkb)
#pragma unroll
        for (int r = 0; r < 4; ++r)
          if (kbase + kkb * 16 + quad * 4 + r > qg) sacc[kkb][r] = -3.0e38f;
    }

    // no-max softmax: p = exp2(s); per-lane partial l
    shortx4 pf[4];
    {
      float psum = 0.f;
#pragma unroll
      for (int kkb = 0; kkb < 4; ++kkb) {
        float p0 = fast_exp2(sacc[kkb][0]);
        float p1 = fast_exp2(sacc[kkb][1]);
        float p2 = fast_exp2(sacc[kkb][2]);
        float p3 = fast_exp2(sacc[kkb][3]);
        psum += (p0 + p1) + (p2 + p3);
        pf[kkb] = mk_sx4(pack2bf(p0, p1), pack2bf(p2, p3));
      }
      l_run += psum;
    }

    // PV (x32, permuted Vt): one b128 per (kp,db) at chunk (4kp+quad)
    // ^ (l16&7); slots i<4 = kkb 2kp, i>=4 = kkb 2kp+1 (r=i&3), matching
    // pf8 = cat44(pf[2kp], pf[2kp+1]). Conflict-free b128 pattern.
    __builtin_amdgcn_s_setprio(1);
#pragma unroll
    for (int kp = 0; kp < 2; ++kp) {
      const shortx8 pf8 = cat44(pf[kp * 2], pf[kp * 2 + 1]);
      const int jj = ((kp * 4 + quad) ^ (l16 & 7)) * 8;  // ushort offset
#pragma unroll
      for (int db = 0; db < 4; ++db) {
        const shortx8 vf8 = *(const shortx8*)(v_lds + (db * 16 + l16) * 64 + jj);
        oacc[db] = __builtin_amdgcn_mfma_f32_16x16x32_bf16(vf8, pf8, oacc[db], 0, 0, 0);
      }
    }
    __builtin_amdgcn_s_setprio(0);
  }

  // epilogue: reduce l across quads, normalize, pack, transpose via LDS
  __syncthreads();
  ushort_t* sm = &smem[0][0];
  {
    float l0 = l_run;
    l0 += __shfl_xor(l0, 16);
    l0 += __shfl_xor(l0, 32);
    float inv_l = 1.0f / l0;
    int row = wave * 16 + l16;  // 0..63
#pragma unroll
    for (int db = 0; db < 4; ++db) {
#pragma unroll
      for (int rr = 0; rr < 2; ++rr) {
        unsigned pk = pack2bf(oacc[db][rr * 2] * inv_l, oacc[db][rr * 2 + 1] * inv_l);
        *(unsigned*)(sm + row * 72 + db * 16 + quad * 4 + rr * 2) = pk;
      }
    }
  }
  __syncthreads();
  {
    int r = tid >> 2, c = (tid & 3) * 16;
    const ushort_t* src = sm + r * 72 + c;
    ushort_t* dst = O + ((size_t)b * S_ + q0 + r) * D_ + hoff + c;
    uint4 v0 = *(const uint4*)(src);
    uint4 v1 = *(const uint4*)(src + 8);
    *(uint4*)(dst) = v0;
    *(uint4*)(dst + 8) = v1;
  }
}

// ---------------------------------------------------------------------------
extern "C" void kernel_launch(void* const* d_in, const int* in_sizes, int n_in,
                              void* d_out, int out_size, void* d_ws, size_t ws_size,
                              hipStream_t stream) {
  (void)in_sizes; (void)n_in; (void)out_size; (void)ws_size;
  char* ws = (char*)d_ws;
  ushort_t* xq = (ushort_t*)(ws + 0);
  ushort_t* xk = (ushort_t*)(ws + 8388608);
  ushort_t* xv = (ushort_t*)(ws + 16777216);
  ushort_t* wq = (ushort_t*)(ws + 25165824);
  ushort_t* wk = (ushort_t*)(ws + 27262976);
  ushort_t* wv = (ushort_t*)(ws + 29360128);
  ushort_t* wo = (ushort_t*)(ws + 31457280);
  ushort_t* Qp = (ushort_t*)(ws + 33554432);
  ushort_t* Kp = (ushort_t*)(ws + 41943040);
  ushort_t* Vt = (ushort_t*)(ws + 50331648);  // V GEMM writes transposed+permuted
  ushort_t* O = xq;   // xq dead after QKV GEMM

  ConvArgs ca;
  ca.src[0] = (const float*)d_in[0];  ca.dst[0] = xq;
  ca.src[1] = (const float*)d_in[1];  ca.dst[1] = xk;
  ca.src[2] = (const float*)d_in[2];  ca.dst[2] = xv;
  ca.src[3] = (const float*)d_in[4];  ca.dst[3] = wq;
  ca.src[4] = (const float*)d_in[6];  ca.dst[4] = wk;
  ca.src[5] = (const float*)d_in[8];  ca.dst[5] = wv;
  ca.src[6] = (const float*)d_in[10]; ca.dst[6] = wo;
  convert_kernel<<<dim3(4096), dim3(256), 0, stream>>>(ca);

  QkvArgs qa;
  qa.A[0] = xq; qa.W[0] = wq; qa.bias[0] = (const float*)d_in[5]; qa.out[0] = Qp;
  qa.A[1] = xk; qa.W[1] = wk; qa.bias[1] = (const float*)d_in[7]; qa.out[1] = Kp;
  qa.A[2] = xv; qa.W[2] = wv; qa.bias[2] = (const float*)d_in[9]; qa.out[2] = Vt;
  qa.scale[0] = 0.125f * 1.44269504089f;  // fold 1/sqrt(dk) * log2(e) into Q
  qa.scale[1] = 1.0f;
  qa.scale[2] = 1.0f;
  gemm_qkv_kernel<<<dim3(8, 64, 3), dim3(256), 0, stream>>>(qa);

  attn_kernel<<<dim3(1024), dim3(256), 0, stream>>>(Qp, Kp, Vt, O);

  gemm_out_kernel<<<dim3(8, 64, 1), dim3(256), 0, stream>>>(
      O, wo, (const float*)d_in[11], (float*)d_out);
}